// Round 13
// baseline (602.489 us; speedup 1.0000x reference)
//
#include <hip/hip_runtime.h>
#include <hip/hip_bf16.h>
#include <stdint.h>

// LSTMCell fused: g = hx @ W + b (M=8192,K=2048,N=7*2048) + gate math.
// R13: m201-template GEMM with gate-permuted B panels. Block = 256 rows x
// (32 h-cols x 7 gates = 224 B-cols); BK=64; 8 waves (4M x 2N), wave =
// 64x112, acc 7x4xf32x4. Per K-tile: 4 phases {ds_read subtile; glds;
// barrier; lgkmcnt(0); setprio; 16-MFMA; setprio; barrier}; one
// vmcnt(0)+barrier publish per tile. Epilogue fused (each thread holds all
// 7 gates for its (row,h)). ws = B-img 58.7MB + A-img 33.5MB = 92,274,688.

#define B_SZ 8192
#define D_SZ 2048
#define H_SZ 2048
#define NG   7
#define NW   (NG * H_SZ)          // 14336
#define BM   256
#define BK   64
#define NKT  (D_SZ / BK)          // 32
#define NBX  (B_SZ / BM)          // 32
#define NNB  (H_SZ / 32)          // 64

#define ATILE 32768               // 256 rows x 64 k bf16
#define BTILE 28672               // 224 cols x 64 k bf16
#define WB_BYTES   ((size_t)NNB * NKT * BTILE)   // 58,720,256
#define AB_OFF     WB_BYTES
#define AB_BYTES   ((size_t)NBX * NKT * ATILE)   // 33,554,432
#define WS_NEEDED  (WB_BYTES + AB_BYTES)         // 92,274,688

typedef __attribute__((ext_vector_type(8))) short bf16x8;
typedef __attribute__((ext_vector_type(4))) float f32x4;

__device__ __forceinline__ uint32_t cvtpk(float lo, float hi) {
    uint32_t r;
    asm("v_cvt_pk_bf16_f32 %0, %1, %2" : "=v"(r) : "v"(lo), "v"(hi));
    return r;
}
__device__ __forceinline__ void glds16(const void* g, void* l) {
    __builtin_amdgcn_global_load_lds(
        (const __attribute__((address_space(1))) uint32_t*)g,
        (__attribute__((address_space(3))) uint32_t*)l, 16, 0, 0);
}
__device__ __forceinline__ float sigmoidf_(float x) {
    return 1.0f / (1.0f + __expf(-x));
}
__device__ __forceinline__ float tanhf_(float x) {
    float ax = fabsf(x);
    float e = __expf(2.0f * ax);
    float t = 1.0f - 2.0f / (e + 1.0f);
    return copysignf(t, x);
}
__device__ __forceinline__ float softplusf_(float x) {
    return (x > 30.0f) ? x : __logf(1.0f + __expf(x));
}

// ---- conv_a: hx -> A image [bx][kt]{256 rows x 64 k}, chunk-swizzled -----
// byte(r, k) = r*128 + ((k>>3) ^ ((r>>1)&3))*16 + (k&7)*2
__global__ __launch_bounds__(512) void conv_a(const float* __restrict__ hx,
                                              char* __restrict__ ai)
{
    const int bx = blockIdx.x >> 5;
    const int kt = blockIdx.x & 31;
    char* dst = ai + (size_t)(bx * NKT + kt) * ATILE;
    #pragma unroll
    for (int i = 0; i < 4; ++i) {
        int d = threadIdx.x + i * 512;       // 0..2047 = 256 rows x 8 chunks
        int r = d >> 3, kq = d & 7;
        int koct = kq ^ ((r >> 1) & 3);
        const float* s = hx + (size_t)(bx * BM + r) * D_SZ + kt * BK + koct * 8;
        f32x4 a = *(const f32x4*)s;
        f32x4 b = *(const f32x4*)(s + 4);
        uint4 o;
        o.x = cvtpk(a[0], a[1]); o.y = cvtpk(a[2], a[3]);
        o.z = cvtpk(b[0], b[1]); o.w = cvtpk(b[2], b[3]);
        *(uint4*)(dst + d * 16) = o;
    }
}

// ---- conv_b: W -> B image [nb][kt]{224 cols x 64 k}, gate-permuted -------
// col c -> gate = (c>>4)%7, hsub = ((c>>4)/7)*16 + (c&15);
// byte(c, k) = c*128 + ((k>>3) ^ ((c>>1)&3))*16 + (k&7)*2
__global__ __launch_bounds__(448) void conv_b(const float* __restrict__ W,
                                              char* __restrict__ bi)
{
    const int nb = blockIdx.x >> 5;
    const int kt = blockIdx.x & 31;
    char* dst = bi + (size_t)(nb * NKT + kt) * BTILE;
    const int cc = threadIdx.x % 224;
    const int kh = threadIdx.x / 224;        // 0..1
    const int q  = cc >> 4;
    const int gate = (q < 7) ? q : q - 7;
    const int hsub = ((q < 7) ? 0 : 16) + (cc & 15);
    const int n = gate * H_SZ + nb * 32 + hsub;
    #pragma unroll
    for (int i = 0; i < 4; ++i) {
        int kq = kh * 4 + i;
        int koct = kq ^ ((cc >> 1) & 3);
        const float* s = W + (size_t)(kt * BK + koct * 8) * NW + n;
        float w0 = s[0];
        float w1 = s[(size_t)NW];
        float w2 = s[(size_t)2 * NW];
        float w3 = s[(size_t)3 * NW];
        float w4 = s[(size_t)4 * NW];
        float w5 = s[(size_t)5 * NW];
        float w6 = s[(size_t)6 * NW];
        float w7 = s[(size_t)7 * NW];
        uint4 o;
        o.x = cvtpk(w0, w1); o.y = cvtpk(w2, w3);
        o.z = cvtpk(w4, w5); o.w = cvtpk(w6, w7);
        *(uint4*)(dst + cc * 128 + kq * 16) = o;
    }
}

// ---- main GEMM + fused gate epilogue --------------------------------------
#define MFMA_ __builtin_amdgcn_mfma_f32_16x16x32_bf16
#define SB0 __builtin_amdgcn_sched_barrier(0)
#define DSR(DST, BASE, OFF) \
    asm volatile("ds_read_b128 %0, %1 offset:" #OFF : "=v"(DST) : "v"(BASE));

__global__ __launch_bounds__(512, 2) void lstm_gemm(
    const char* __restrict__ bi, const char* __restrict__ ai,
    const float* __restrict__ cx1, const float* __restrict__ cx2,
    const float* __restrict__ dt, const float* __restrict__ bias,
    float* __restrict__ out)
{
    __shared__ char smem[2 * 61440];   // 2 x (A 32KB + B 28KB) = 122880

    const int tid  = threadIdx.x;
    const int lane = tid & 63;
    const int wid  = tid >> 6;          // 0..7
    const int wm4  = wid >> 1;          // 0..3: rows wm4*64..+64
    const int wn2  = wid & 1;           // 0..1: cols wn2*112..+112
    const int l15  = lane & 15;
    const int lg   = lane >> 4;

    // block order: XCD chunk; nb fast within chunk (A panel 1MB L2-hot/bx)
    const int b0  = blockIdx.x;
    const int swz = (b0 & 7) * 256 + (b0 >> 3);
    const int bx  = swz >> 6;           // 0..31
    const int nb  = swz & 63;           // 0..63

    // fragment LDS addresses; xch = lg ^ ((row>>1)&3) (proven 0-conflict)
    const int xch = lg ^ ((l15 >> 1) & 3);
    const uint32_t aA0 = (uint32_t)(uintptr_t)smem + wm4 * 8192 + l15 * 128 + xch * 16;
    const uint32_t aA1 = aA0 + 61440;
    const uint32_t aB0 = (uint32_t)(uintptr_t)smem + 32768 + wn2 * 14336 + l15 * 128 + xch * 16;
    const uint32_t aB1 = aB0 + 61440;

    // staging dst (wave-uniform LDS bases)
    char* dstA0 = smem + (wid << 12);             // 4KB/wave x 8 = 32KB
    char* dstA1 = dstA0 + 61440;
    char* dstB0 = smem + 32768 + wid * 3584;      // 3.5KB/wave x 8 = 28KB
    char* dstB1 = dstB0 + 61440;

    // staging src (per-lane global)
    const char* qa = ai + (size_t)bx * (NKT * ATILE) + (wid << 12) + (lane << 4);
    const char* qb = bi + (size_t)nb * (NKT * BTILE) + wid * 3584 + (lane << 4);

    f32x4 acc[NG][4];
    #pragma unroll
    for (int g = 0; g < NG; ++g)
        #pragma unroll
        for (int mf = 0; mf < 4; ++mf)
            acc[g][mf] = (f32x4){0.f, 0.f, 0.f, 0.f};

    bf16x8 fA[4][2], fB0[2], fB1[2];

    #define RD_A(AA) \
        DSR(fA[0][0], AA, 0)    DSR(fA[0][1], AA, 64) \
        DSR(fA[1][0], AA, 2048) DSR(fA[1][1], AA, 2112) \
        DSR(fA[2][0], AA, 4096) DSR(fA[2][1], AA, 4160) \
        DSR(fA[3][0], AA, 6144) DSR(fA[3][1], AA, 6208)

    #define RD_B2(AB, O0, O1, O2, O3) \
        DSR(fB0[0], AB, O0) DSR(fB0[1], AB, O1) \
        DSR(fB1[0], AB, O2) DSR(fB1[1], AB, O3)

    #define PH_SYNC \
        SB0; __builtin_amdgcn_s_barrier(); \
        asm volatile("s_waitcnt lgkmcnt(0)" ::: "memory"); SB0;

    #define CL16(NA, NX) \
        __builtin_amdgcn_s_setprio(1); \
        _Pragma("unroll") \
        for (int mf_ = 0; mf_ < 4; ++mf_) { \
            acc[NA][mf_] = MFMA_(fA[mf_][0], fB0[0], acc[NA][mf_], 0, 0, 0); \
            acc[NA][mf_] = MFMA_(fA[mf_][1], fB0[1], acc[NA][mf_], 0, 0, 0); \
        } \
        _Pragma("unroll") \
        for (int mf_ = 0; mf_ < 4; ++mf_) { \
            acc[NX][mf_] = MFMA_(fA[mf_][0], fB1[0], acc[NX][mf_], 0, 0, 0); \
            acc[NX][mf_] = MFMA_(fA[mf_][1], fB1[1], acc[NX][mf_], 0, 0, 0); \
        } \
        __builtin_amdgcn_s_setprio(0); SB0;

    #define STG_A(NB_) do { \
        glds16(psA, dstA##NB_);            glds16(psA + 1024, dstA##NB_ + 1024); \
        glds16(psA + 2048, dstA##NB_ + 2048); glds16(psA + 3072, dstA##NB_ + 3072); \
        psA += ATILE; } while (0)

    #define STG_B(NB_) do { \
        glds16(psB, dstB##NB_);            glds16(psB + 1024, dstB##NB_ + 1024); \
        glds16(psB + 2048, dstB##NB_ + 2048); \
        if (lane < 32) glds16(psB + 3072, dstB##NB_ + 3072); \
        psB += BTILE; } while (0)

    // One K-64 tile from buf B_, staging next tile into buf N_ (if STG).
    #define TILE(B_, N_, STG) do { \
        /* ph0: A subtile (8) + B nf0,1 (4); stage next-A */ \
        RD_A(aA##B_) \
        RD_B2(aB##B_, 0, 64, 2048, 2112) \
        if (STG) STG_A(N_); \
        PH_SYNC \
        CL16(0, 1) \
        __builtin_amdgcn_s_barrier(); \
        /* ph1: B nf2,3; stage next-B */ \
        RD_B2(aB##B_, 4096, 4160, 6144, 6208) \
        if (STG) STG_B(N_); \
        PH_SYNC \
        CL16(2, 3) \
        __builtin_amdgcn_s_barrier(); \
        /* ph2: B nf4,5 */ \
        RD_B2(aB##B_, 8192, 8256, 10240, 10304) \
        PH_SYNC \
        CL16(4, 5) \
        __builtin_amdgcn_s_barrier(); \
        /* ph3: B nf6; publish next tile */ \
        DSR(fB0[0], aB##B_, 12288) DSR(fB0[1], aB##B_, 12352) \
        PH_SYNC \
        __builtin_amdgcn_s_setprio(1); \
        _Pragma("unroll") \
        for (int mf_ = 0; mf_ < 4; ++mf_) { \
            acc[6][mf_] = MFMA_(fA[mf_][0], fB0[0], acc[6][mf_], 0, 0, 0); \
            acc[6][mf_] = MFMA_(fA[mf_][1], fB0[1], acc[6][mf_], 0, 0, 0); \
        } \
        __builtin_amdgcn_s_setprio(0); SB0; \
        asm volatile("s_waitcnt vmcnt(0)" ::: "memory"); \
        __builtin_amdgcn_s_barrier(); \
        SB0; \
    } while (0)

    // prologue: stage tile 0 -> buf0; publish
    glds16(qa, dstA0);        glds16(qa + 1024, dstA0 + 1024);
    glds16(qa + 2048, dstA0 + 2048); glds16(qa + 3072, dstA0 + 3072);
    glds16(qb, dstB0);        glds16(qb + 1024, dstB0 + 1024);
    glds16(qb + 2048, dstB0 + 2048);
    if (lane < 32) glds16(qb + 3072, dstB0 + 3072);
    const char* psA = qa + ATILE;
    const char* psB = qb + BTILE;
    asm volatile("s_waitcnt vmcnt(0)" ::: "memory");
    __builtin_amdgcn_s_barrier();
    SB0;

    #pragma unroll 1
    for (int it = 0; it < 16; ++it) {
        TILE(0, 1, 1);              // even tile: buf0, stage odd -> buf1
        TILE(1, 0, (it < 15));      // odd tile: buf1, stage even -> buf0
    }

    // fused epilogue: thread holds all 7 gates for its (row, h) set
    const size_t BH = (size_t)B_SZ * H_SZ;
    const int h = nb * 32 + wn2 * 16 + l15;
    float bj[NG];
    #pragma unroll
    for (int g = 0; g < NG; ++g) bj[g] = bias[g * H_SZ + h];

    #pragma unroll
    for (int mf = 0; mf < 4; ++mf) {
        #pragma unroll
        for (int r = 0; r < 4; ++r) {
            int row = bx * BM + wm4 * 64 + mf * 16 + lg * 4 + r;
            float dtv = dt[row];
            float i1 = sigmoidf_(acc[0][mf][r] + bj[0]);
            float i2 = sigmoidf_(acc[1][mf][r] + bj[1]);
            float f1 = sigmoidf_(acc[2][mf][r] + bj[2]);
            float f2 = sigmoidf_(acc[3][mf][r] + bj[3]);
            float o  = sigmoidf_(acc[4][mf][r] + bj[4]);
            float z  = tanhf_(acc[5][mf][r] + bj[5]);
            float dec = softplusf_(acc[6][mf][r] + bj[6]);
            size_t idx = (size_t)row * H_SZ + h;
            float c1 = cx1[idx], c2 = cx2[idx];
            float cy1 = f1 * c1 + i1 * z;
            float cy2 = f2 * c2 + i2 * z;
            float ct  = cy2 + (cy1 - cy2) * __expf(-dec * dtv);
            float ht  = o * tanhf_(ct);
            out[idx]          = cy1;
            out[BH + idx]     = cy2;
            out[2 * BH + idx] = ht;
        }
    }
}

// ---------------- f32 fallback (R2, passed) --------------------------------
#define BN_  32
#define NTH  512
#define LDP  40
#define NKST 64
__global__ __launch_bounds__(NTH, 2) void lstm_f32(
    const float* __restrict__ hx, const float* __restrict__ cx1,
    const float* __restrict__ cx2, const float* __restrict__ dt,
    const float* __restrict__ W, const float* __restrict__ bias,
    float* __restrict__ out)
{
    __shared__ ushort sA[BM * LDP];
    __shared__ ushort sB[NG * BN_ * LDP];

    const int tid = threadIdx.x;
    const int nwg = gridDim.x;
    const int cpx = nwg >> 3;
    const int b0  = blockIdx.x;
    const int swz = (b0 & 7) * cpx + (b0 >> 3);
    const int bx  = swz & 31;
    const int by  = swz >> 5;
    const int gm0 = bx * BM;
    const int n0  = by * BN_;

    const int lane = tid & 63;
    const int wid  = tid >> 6;
    const int wm   = wid >> 1;
    const int wn   = wid & 1;
    const int l15  = lane & 15;
    const int lg   = lane >> 4;

    const int ar0 = tid >> 2,          aq0 = tid & 3;
    const int ar1 = (tid + 512) >> 2,  aq1 = tid & 3;
    const bool hasB = (tid < 448);
    const int bg  = tid >> 6;
    const int bkq = (tid >> 3) & 7;
    const int bnq = tid & 7;

    f32x4 pa[4];
    f32x4 pb[4];

    auto issue_loads = [&](int K0) {
        {
            const float* p = hx + (size_t)(gm0 + ar0) * D_SZ + K0 + aq0 * 8;
            pa[0] = *(const f32x4*)(p);
            pa[1] = *(const f32x4*)(p + 4);
        }
        {
            const float* p = hx + (size_t)(gm0 + ar1) * D_SZ + K0 + aq1 * 8;
            pa[2] = *(const f32x4*)(p);
            pa[3] = *(const f32x4*)(p + 4);
        }
        if (hasB) {
            const float* p = W + (size_t)(K0 + bkq * 4) * NW + bg * H_SZ + n0 + bnq * 4;
            pb[0] = *(const f32x4*)(p);
            pb[1] = *(const f32x4*)(p + NW);
            pb[2] = *(const f32x4*)(p + 2 * NW);
            pb[3] = *(const f32x4*)(p + 3 * NW);
        }
    };

    auto store_lds = [&]() {
        {
            uint4 u;
            u.x = cvtpk(pa[0][0], pa[0][1]); u.y = cvtpk(pa[0][2], pa[0][3]);
            u.z = cvtpk(pa[1][0], pa[1][1]); u.w = cvtpk(pa[1][2], pa[1][3]);
            *(uint4*)(&sA[ar0 * LDP + aq0 * 8]) = u;
        }
        {
            uint4 u;
            u.x = cvtpk(pa[2][0], pa[2][1]); u.y = cvtpk(pa[2][2], pa[2][3]);
            u.z = cvtpk(pa[3][0], pa[3][1]); u.w = cvtpk(pa[3][2], pa[3][3]);
            *(uint4*)(&sA[ar1 * LDP + aq1 * 8]) = u;
        }
        if (hasB) {
            #pragma unroll
            for (int jj = 0; jj < 4; ++jj) {
                uint2 v;
                v.x = cvtpk(pb[0][jj], pb[1][jj]);
                v.y = cvtpk(pb[2][jj], pb[3][jj]);
                *(uint2*)(&sB[(bg * BN_ + bnq * 4 + jj) * LDP + bkq * 4]) = v;
            }
        }
    };

    f32x4 acc[NG][4];
    #pragma unroll
    for (int g = 0; g < NG; ++g)
        #pragma unroll
        for (int mf = 0; mf < 4; ++mf)
            acc[g][mf] = (f32x4){0.f, 0.f, 0.f, 0.f};

    int aoff[4];
    #pragma unroll
    for (int mf = 0; mf < 4; ++mf)
        aoff[mf] = (wm * 64 + mf * 16 + l15) * LDP + lg * 8;
    int boff[NG];
    #pragma unroll
    for (int g = 0; g < NG; ++g)
        boff[g] = (g * BN_ + wn * 16 + l15) * LDP + lg * 8;

    issue_loads(0);
    for (int kk = 0; kk < NKST; ++kk) {
        store_lds();
        __syncthreads();
        if (kk + 1 < NKST) issue_loads((kk + 1) * 32);

        bf16x8 af[4];
        #pragma unroll
        for (int mf = 0; mf < 4; ++mf)
            af[mf] = *(const bf16x8*)(&sA[aoff[mf]]);
        #pragma unroll
        for (int g = 0; g < NG; ++g) {
            bf16x8 bfr = *(const bf16x8*)(&sB[boff[g]]);
            #pragma unroll
            for (int mf = 0; mf < 4; ++mf)
                acc[g][mf] = __builtin_amdgcn_mfma_f32_16x16x32_bf16(
                    af[mf], bfr, acc[g][mf], 0, 0, 0);
        }
        __syncthreads();
    }

    const size_t BH = (size_t)B_SZ * H_SZ;
    const int j = n0 + wn * 16 + l15;
    float bj[NG];
    #pragma unroll
    for (int g = 0; g < NG; ++g) bj[g] = bias[g * H_SZ + j];

    #pragma unroll
    for (int mf = 0; mf < 4; ++mf) {
        #pragma unroll
        for (int r = 0; r < 4; ++r) {
            int row = gm0 + wm * 64 + mf * 16 + lg * 4 + r;
            float dtv = dt[row];
            float i1 = sigmoidf_(acc[0][mf][r] + bj[0]);
            float i2 = sigmoidf_(acc[1][mf][r] + bj[1]);
            float f1 = sigmoidf_(acc[2][mf][r] + bj[2]);
            float f2 = sigmoidf_(acc[3][mf][r] + bj[3]);
            float o  = sigmoidf_(acc[4][mf][r] + bj[4]);
            float z  = tanhf_(acc[5][mf][r] + bj[5]);
            float dec = softplusf_(acc[6][mf][r] + bj[6]);
            size_t idx = (size_t)row * H_SZ + j;
            float c1 = cx1[idx], c2 = cx2[idx];
            float cy1 = f1 * c1 + i1 * z;
            float cy2 = f2 * c2 + i2 * z;
            float ct  = cy2 + (cy1 - cy2) * __expf(-dec * dtv);
            float ht  = o * tanhf_(ct);
            out[idx]          = cy1;
            out[BH + idx]     = cy2;
            out[2 * BH + idx] = ht;
        }
    }
}

extern "C" void kernel_launch(void* const* d_in, const int* in_sizes, int n_in,
                              void* d_out, int out_size, void* d_ws, size_t ws_size,
                              hipStream_t stream) {
    const float* hx  = (const float*)d_in[0];
    const float* cx1 = (const float*)d_in[1];
    const float* cx2 = (const float*)d_in[2];
    const float* dt  = (const float*)d_in[4];
    const float* W   = (const float*)d_in[5];
    const float* b   = (const float*)d_in[6];
    float* out = (float*)d_out;

    if (ws_size >= WS_NEEDED) {
        char* bimg = (char*)d_ws;
        char* aimg = (char*)d_ws + AB_OFF;
        conv_b<<<dim3(NNB * NKT), dim3(448), 0, stream>>>(W, bimg);
        conv_a<<<dim3(NBX * NKT), dim3(512), 0, stream>>>(hx, aimg);
        lstm_gemm<<<dim3(NBX * NNB), dim3(512), 0, stream>>>(
            bimg, aimg, cx1, cx2, dt, b, out);
    } else {
        lstm_f32<<<dim3(NBX * NNB / 2), dim3(NTH), 0, stream>>>(
            hx, cx1, cx2, dt, W, b, out);
    }
}

// Round 14
// 564.642 us; speedup vs baseline: 1.0670x; 1.0670x over previous
//
#include <hip/hip_runtime.h>
#include <hip/hip_bf16.h>
#include <stdint.h>

// LSTMCell fused: g = hx @ W + b (M=8192,K=2048,N=7*2048) + gate math.
// R14: m201 phase template with PROVEN layout restored. Block = 256 rows x
// 224 gate-permuted B-cols, BK=64 (2 K-32 subtiles, 64B rows, proven
// xch = lg^((l15>>1)&3) swizzle -- 0 conflicts in R4-R12). 8 waves 4Mx2N.
// Per tile: 4 phases {ds_read 8|3; stage 1 unit (2 glds); barrier; lgkm0;
// setprio 16|12-MFMA; barrier}; publishes via COUNTED vmcnt(4) at ph0/ph2
// entries (never 0 mid-loop). R4 block ordering (by-pairs, bx fast).

#define B_SZ 8192
#define D_SZ 2048
#define H_SZ 2048
#define NG   7
#define NW   (NG * H_SZ)          // 14336
#define BM   256
#define NKT  32                   // K-64 tiles
#define NBX  (B_SZ / BM)          // 32
#define NNB  (H_SZ / 32)          // 64

#define ATILE 32768               // 2 x (256 rows x 32 k) subtiles
#define BTILE 28672               // 2 x (224 cols x 32 k) subtiles
#define WB_BYTES   ((size_t)NNB * NKT * BTILE)   // 58,720,256
#define AB_OFF     WB_BYTES
#define AB_BYTES   ((size_t)NBX * NKT * ATILE)   // 33,554,432
#define WS_NEEDED  (WB_BYTES + AB_BYTES)         // 92,274,688

typedef __attribute__((ext_vector_type(8))) short bf16x8;
typedef __attribute__((ext_vector_type(4))) float f32x4;

__device__ __forceinline__ uint32_t cvtpk(float lo, float hi) {
    uint32_t r;
    asm("v_cvt_pk_bf16_f32 %0, %1, %2" : "=v"(r) : "v"(lo), "v"(hi));
    return r;
}
__device__ __forceinline__ void glds16(const void* g, void* l) {
    __builtin_amdgcn_global_load_lds(
        (const __attribute__((address_space(1))) uint32_t*)g,
        (__attribute__((address_space(3))) uint32_t*)l, 16, 0, 0);
}
__device__ __forceinline__ float sigmoidf_(float x) {
    return 1.0f / (1.0f + __expf(-x));
}
__device__ __forceinline__ float tanhf_(float x) {
    float ax = fabsf(x);
    float e = __expf(2.0f * ax);
    float t = 1.0f - 2.0f / (e + 1.0f);
    return copysignf(t, x);
}
__device__ __forceinline__ float softplusf_(float x) {
    return (x > 30.0f) ? x : __logf(1.0f + __expf(x));
}

// ---- conv_a: hx -> A image [bx][ks(64)] {256 rows x 32 k}, 64B rows -------
// stored slot (r, pc) holds logical k-octet pc ^ ((r>>1)&3)   (R4-proven)
__global__ __launch_bounds__(1024) void conv_a(const float* __restrict__ hx,
                                               char* __restrict__ ai)
{
    const int bx = blockIdx.x >> 6;
    const int ks = blockIdx.x & 63;
    const int u  = threadIdx.x;          // 0..1023 = 256 rows x 4 chunks
    const int r  = u >> 2;
    const int pc = u & 3;
    const int koct = pc ^ ((r >> 1) & 3);
    const float* src = hx + (size_t)(bx * BM + r) * D_SZ + ks * 32 + koct * 8;
    f32x4 a = *(const f32x4*)(src);
    f32x4 b = *(const f32x4*)(src + 4);
    uint4 o;
    o.x = cvtpk(a[0], a[1]); o.y = cvtpk(a[2], a[3]);
    o.z = cvtpk(b[0], b[1]); o.w = cvtpk(b[2], b[3]);
    *(uint4*)(ai + (size_t)blockIdx.x * 16384 + u * 16) = o;
}

// ---- conv_b: W -> B image [nb][kt(32)] {2 x (224 cols x 32 k)}, permuted --
// col c -> gate = (c>>4)%7, hsub = ((c>>4)/7)*16 + (c&15)
// stored slot (sub, c, pc) holds logical k-octet pc ^ ((c>>1)&3)
__global__ __launch_bounds__(448) void conv_b(const float* __restrict__ W,
                                              char* __restrict__ bi)
{
    const int nb = blockIdx.x >> 5;
    const int kt = blockIdx.x & 31;
    char* dst = bi + (size_t)blockIdx.x * BTILE;
    const int cc = threadIdx.x % 224;
    const int kh = threadIdx.x / 224;        // K-32 subtile 0/1
    const int q  = cc >> 4;
    const int gate = (q < 7) ? q : q - 7;
    const int hsub = ((q < 7) ? 0 : 16) + (cc & 15);
    const int n  = gate * H_SZ + nb * 32 + hsub;
    const int xb = (cc >> 1) & 3;
    #pragma unroll
    for (int pc = 0; pc < 4; ++pc) {
        const int k = kt * 64 + kh * 32 + (pc ^ xb) * 8;
        const float* s = W + (size_t)k * NW + n;
        float w0 = s[0];
        float w1 = s[(size_t)NW];
        float w2 = s[(size_t)2 * NW];
        float w3 = s[(size_t)3 * NW];
        float w4 = s[(size_t)4 * NW];
        float w5 = s[(size_t)5 * NW];
        float w6 = s[(size_t)6 * NW];
        float w7 = s[(size_t)7 * NW];
        uint4 o;
        o.x = cvtpk(w0, w1); o.y = cvtpk(w2, w3);
        o.z = cvtpk(w4, w5); o.w = cvtpk(w6, w7);
        *(uint4*)(dst + kh * 14336 + cc * 64 + pc * 16) = o;
    }
}

// ---- main GEMM + fused gate epilogue --------------------------------------
#define MFMA_ __builtin_amdgcn_mfma_f32_16x16x32_bf16
#define SB0 __builtin_amdgcn_sched_barrier(0)
#define DSR(DST, BASE, OFF) \
    asm volatile("ds_read_b128 %0, %1 offset:" #OFF : "=v"(DST) : "v"(BASE));

__global__ __launch_bounds__(512, 2) void lstm_gemm(
    const char* __restrict__ bi, const char* __restrict__ ai,
    const float* __restrict__ cx1, const float* __restrict__ cx2,
    const float* __restrict__ dt, const float* __restrict__ bias,
    float* __restrict__ out)
{
    __shared__ char smem[2 * 61440];   // per buf: A 32KB (2x16K) + B 28KB (2x14K)

    const int tid  = threadIdx.x;
    const int lane = tid & 63;
    const int wid  = tid >> 6;          // 0..7
    const int wm4  = wid >> 1;          // 0..3: rows wm4*64..+64
    const int wn2  = wid & 1;           // 0..1: B-cols wn2*112..+112
    const int l15  = lane & 15;
    const int lg   = lane >> 4;

    // R4-proven ordering: XCD chunk; nb-pairs; bx fast within chunk
    const int b0  = blockIdx.x;
    const int swz = (b0 & 7) * 256 + (b0 >> 3);
    const int nb2 = swz >> 6;           // 0..31
    const int rem = swz & 63;
    const int bx  = rem >> 1;           // 0..31
    const int nb  = nb2 * 2 + (rem & 1);// 0..63

    // fragment LDS byte addresses (proven swizzle; 64B rows)
    const int xch = lg ^ ((l15 >> 1) & 3);
    const uint32_t aAb = (uint32_t)(uintptr_t)smem
                       + (wm4 * 64 + l15) * 64 + xch * 16;
    const uint32_t aBb = (uint32_t)(uintptr_t)smem + 32768
                       + (wn2 * 112 + l15) * 64 + xch * 16;
    const uint32_t aA0 = aAb, aA1 = aAb + 61440;
    const uint32_t aB0 = aBb, aB1 = aBb + 61440;

    // staging: per-wave slices (A-sub 2KB = 2 glds; B-sub 1.75KB = 2 glds)
    const int lane16 = lane << 4;
    const char* qa = ai + ((size_t)bx << 20) + (wid << 11) + lane16;
    const char* qb = bi + (size_t)nb * (NKT * BTILE) + wid * 1792 + lane16;
    char* dA0 = smem + (wid << 11);            char* dA1 = dA0 + 61440;
    char* dB0 = smem + 32768 + wid * 1792;     char* dB1 = dB0 + 61440;

    f32x4 acc[NG][4];
    #pragma unroll
    for (int g = 0; g < NG; ++g)
        #pragma unroll
        for (int mf = 0; mf < 4; ++mf)
            acc[g][mf] = (f32x4){0.f, 0.f, 0.f, 0.f};

    bf16x8 fA[4], fB[4];

    #define CL16 \
        __builtin_amdgcn_s_setprio(1); \
        _Pragma("unroll") \
        for (int nf_ = 0; nf_ < 4; ++nf_) \
            _Pragma("unroll") \
            for (int mf_ = 0; mf_ < 4; ++mf_) \
                acc[nf_][mf_] = MFMA_(fA[mf_], fB[nf_], acc[nf_][mf_], 0, 0, 0); \
        __builtin_amdgcn_s_setprio(0); SB0;

    #define CL12 \
        __builtin_amdgcn_s_setprio(1); \
        _Pragma("unroll") \
        for (int nf_ = 0; nf_ < 3; ++nf_) \
            _Pragma("unroll") \
            for (int mf_ = 0; mf_ < 4; ++mf_) \
                acc[4 + nf_][mf_] = MFMA_(fA[mf_], fB[nf_], acc[4 + nf_][mf_], 0, 0, 0); \
        __builtin_amdgcn_s_setprio(0); SB0;

    #define PH_SYNC \
        SB0; \
        __builtin_amdgcn_s_barrier(); \
        asm volatile("s_waitcnt lgkmcnt(0)" ::: "memory"); SB0;

    // one K-64 tile: buf K, stage tile t+1 units into buf N (if STG);
    // VM2 = vmcnt at ph2 entry (4 steady, 0 on last tile)
    #define TILE(K, N, STG, VM2) do { \
        /* --- ph0 entry: publish sub0 of this tile --- */ \
        asm volatile("s_waitcnt vmcnt(4)" ::: "memory"); \
        __builtin_amdgcn_s_barrier(); SB0; \
        DSR(fA[0], aA##K, 0)     DSR(fA[1], aA##K, 1024) \
        DSR(fA[2], aA##K, 2048)  DSR(fA[3], aA##K, 3072) \
        DSR(fB[0], aB##K, 0)     DSR(fB[1], aB##K, 1024) \
        DSR(fB[2], aB##K, 2048)  DSR(fB[3], aB##K, 3072) \
        if (STG) { glds16(psA, dA##N); glds16(psA + 1024, dA##N + 1024); } \
        PH_SYNC \
        CL16 \
        __builtin_amdgcn_s_barrier(); \
        /* --- ph1 --- */ \
        DSR(fB[0], aB##K, 4096)  DSR(fB[1], aB##K, 5120)  DSR(fB[2], aB##K, 6144) \
        if (STG) { glds16(psB, dB##N); if (lane < 48) glds16(psB + 1024, dB##N + 1024); } \
        PH_SYNC \
        CL12 \
        /* --- ph2 entry: publish sub1 --- */ \
        asm volatile("s_waitcnt vmcnt(" #VM2 ")" ::: "memory"); \
        __builtin_amdgcn_s_barrier(); SB0; \
        DSR(fA[0], aA##K, 16384) DSR(fA[1], aA##K, 17408) \
        DSR(fA[2], aA##K, 18432) DSR(fA[3], aA##K, 19456) \
        DSR(fB[0], aB##K, 14336) DSR(fB[1], aB##K, 15360) \
        DSR(fB[2], aB##K, 16384) DSR(fB[3], aB##K, 17408) \
        if (STG) { glds16(psA + 16384, dA##N + 16384); \
                   glds16(psA + 17408, dA##N + 17408); } \
        PH_SYNC \
        CL16 \
        __builtin_amdgcn_s_barrier(); \
        /* --- ph3 --- */ \
        DSR(fB[0], aB##K, 18432) DSR(fB[1], aB##K, 19456) DSR(fB[2], aB##K, 20480) \
        if (STG) { glds16(psB + 14336, dB##N + 14336); \
                   if (lane < 48) glds16(psB + 15360, dB##N + 15360); \
                   psA += ATILE; psB += BTILE; } \
        PH_SYNC \
        CL12 \
    } while (0)

    // prologue: stage tile 0 (order A0,B0,A1,B1 = 8 glds/wave)
    glds16(qa, dA0);           glds16(qa + 1024, dA0 + 1024);
    glds16(qb, dB0);           if (lane < 48) glds16(qb + 1024, dB0 + 1024);
    glds16(qa + 16384, dA0 + 16384); glds16(qa + 17408, dA0 + 17408);
    glds16(qb + 14336, dB0 + 14336);
    if (lane < 48) glds16(qb + 15360, dB0 + 15360);
    const char* psA = qa + ATILE;
    const char* psB = qb + BTILE;

    #pragma unroll 1
    for (int it = 0; it < 15; ++it) {
        TILE(0, 1, 1, 4);       // even tile
        TILE(1, 0, 1, 4);       // odd tile
    }
    TILE(0, 1, 1, 4);           // tile 30, stages tile 31 -> buf1
    TILE(1, 0, 0, 0);           // tile 31 (no staging; final drain)

    // fused epilogue: thread holds all 7 gates for its (row, h) set
    const size_t BH = (size_t)B_SZ * H_SZ;
    const int h = nb * 32 + wn2 * 16 + l15;
    float bj[NG];
    #pragma unroll
    for (int g = 0; g < NG; ++g) bj[g] = bias[g * H_SZ + h];

    #pragma unroll
    for (int mf = 0; mf < 4; ++mf) {
        #pragma unroll
        for (int r = 0; r < 4; ++r) {
            int row = bx * BM + wm4 * 64 + mf * 16 + lg * 4 + r;
            float dtv = dt[row];
            float i1 = sigmoidf_(acc[0][mf][r] + bj[0]);
            float i2 = sigmoidf_(acc[1][mf][r] + bj[1]);
            float f1 = sigmoidf_(acc[2][mf][r] + bj[2]);
            float f2 = sigmoidf_(acc[3][mf][r] + bj[3]);
            float o  = sigmoidf_(acc[4][mf][r] + bj[4]);
            float z  = tanhf_(acc[5][mf][r] + bj[5]);
            float dec = softplusf_(acc[6][mf][r] + bj[6]);
            size_t idx = (size_t)row * H_SZ + h;
            float c1 = cx1[idx], c2 = cx2[idx];
            float cy1 = f1 * c1 + i1 * z;
            float cy2 = f2 * c2 + i2 * z;
            float ct  = cy2 + (cy1 - cy2) * __expf(-dec * dtv);
            float ht  = o * tanhf_(ct);
            out[idx]          = cy1;
            out[BH + idx]     = cy2;
            out[2 * BH + idx] = ht;
        }
    }
}

// ---------------- f32 fallback (R2, passed) --------------------------------
#define BN_  32
#define NTH  512
#define LDP  40
#define NKST 64
__global__ __launch_bounds__(NTH, 2) void lstm_f32(
    const float* __restrict__ hx, const float* __restrict__ cx1,
    const float* __restrict__ cx2, const float* __restrict__ dt,
    const float* __restrict__ W, const float* __restrict__ bias,
    float* __restrict__ out)
{
    __shared__ ushort sA[BM * LDP];
    __shared__ ushort sB[NG * BN_ * LDP];

    const int tid = threadIdx.x;
    const int nwg = gridDim.x;
    const int cpx = nwg >> 3;
    const int b0  = blockIdx.x;
    const int swz = (b0 & 7) * cpx + (b0 >> 3);
    const int bx  = swz & 31;
    const int by  = swz >> 5;
    const int gm0 = bx * BM;
    const int n0  = by * BN_;

    const int lane = tid & 63;
    const int wid  = tid >> 6;
    const int wm   = wid >> 1;
    const int wn   = wid & 1;
    const int l15  = lane & 15;
    const int lg   = lane >> 4;

    const int ar0 = tid >> 2,          aq0 = tid & 3;
    const int ar1 = (tid + 512) >> 2,  aq1 = tid & 3;
    const bool hasB = (tid < 448);
    const int bg  = tid >> 6;
    const int bkq = (tid >> 3) & 7;
    const int bnq = tid & 7;

    f32x4 pa[4];
    f32x4 pb[4];

    auto issue_loads = [&](int K0) {
        {
            const float* p = hx + (size_t)(gm0 + ar0) * D_SZ + K0 + aq0 * 8;
            pa[0] = *(const f32x4*)(p);
            pa[1] = *(const f32x4*)(p + 4);
        }
        {
            const float* p = hx + (size_t)(gm0 + ar1) * D_SZ + K0 + aq1 * 8;
            pa[2] = *(const f32x4*)(p);
            pa[3] = *(const f32x4*)(p + 4);
        }
        if (hasB) {
            const float* p = W + (size_t)(K0 + bkq * 4) * NW + bg * H_SZ + n0 + bnq * 4;
            pb[0] = *(const f32x4*)(p);
            pb[1] = *(const f32x4*)(p + NW);
            pb[2] = *(const f32x4*)(p + 2 * NW);
            pb[3] = *(const f32x4*)(p + 3 * NW);
        }
    };

    auto store_lds = [&]() {
        {
            uint4 u;
            u.x = cvtpk(pa[0][0], pa[0][1]); u.y = cvtpk(pa[0][2], pa[0][3]);
            u.z = cvtpk(pa[1][0], pa[1][1]); u.w = cvtpk(pa[1][2], pa[1][3]);
            *(uint4*)(&sA[ar0 * LDP + aq0 * 8]) = u;
        }
        {
            uint4 u;
            u.x = cvtpk(pa[2][0], pa[2][1]); u.y = cvtpk(pa[2][2], pa[2][3]);
            u.z = cvtpk(pa[3][0], pa[3][1]); u.w = cvtpk(pa[3][2], pa[3][3]);
            *(uint4*)(&sA[ar1 * LDP + aq1 * 8]) = u;
        }
        if (hasB) {
            #pragma unroll
            for (int jj = 0; jj < 4; ++jj) {
                uint2 v;
                v.x = cvtpk(pb[0][jj], pb[1][jj]);
                v.y = cvtpk(pb[2][jj], pb[3][jj]);
                *(uint2*)(&sB[(bg * BN_ + bnq * 4 + jj) * LDP + bkq * 4]) = v;
            }
        }
    };

    f32x4 acc[NG][4];
    #pragma unroll
    for (int g = 0; g < NG; ++g)
        #pragma unroll
        for (int mf = 0; mf < 4; ++mf)
            acc[g][mf] = (f32x4){0.f, 0.f, 0.f, 0.f};

    int aoff[4];
    #pragma unroll
    for (int mf = 0; mf < 4; ++mf)
        aoff[mf] = (wm * 64 + mf * 16 + l15) * LDP + lg * 8;
    int boff[NG];
    #pragma unroll
    for (int g = 0; g < NG; ++g)
        boff[g] = (g * BN_ + wn * 16 + l15) * LDP + lg * 8;

    issue_loads(0);
    for (int kk = 0; kk < NKST; ++kk) {
        store_lds();
        __syncthreads();
        if (kk + 1 < NKST) issue_loads((kk + 1) * 32);

        bf16x8 af[4];
        #pragma unroll
        for (int mf = 0; mf < 4; ++mf)
            af[mf] = *(const bf16x8*)(&sA[aoff[mf]]);
        #pragma unroll
        for (int g = 0; g < NG; ++g) {
            bf16x8 bfr = *(const bf16x8*)(&sB[boff[g]]);
            #pragma unroll
            for (int mf = 0; mf < 4; ++mf)
                acc[g][mf] = __builtin_amdgcn_mfma_f32_16x16x32_bf16(
                    af[mf], bfr, acc[g][mf], 0, 0, 0);
        }
        __syncthreads();
    }

    const size_t BH = (size_t)B_SZ * H_SZ;
    const int j = n0 + wn * 16 + l15;
    float bj[NG];
    #pragma unroll
    for (int g = 0; g < NG; ++g) bj[g] = bias[g * H_SZ + j];

    #pragma unroll
    for (int mf = 0; mf < 4; ++mf) {
        #pragma unroll
        for (int r = 0; r < 4; ++r) {
            int row = gm0 + wm * 64 + mf * 16 + lg * 4 + r;
            float dtv = dt[row];
            float i1 = sigmoidf_(acc[0][mf][r] + bj[0]);
            float i2 = sigmoidf_(acc[1][mf][r] + bj[1]);
            float f1 = sigmoidf_(acc[2][mf][r] + bj[2]);
            float f2 = sigmoidf_(acc[3][mf][r] + bj[3]);
            float o  = sigmoidf_(acc[4][mf][r] + bj[4]);
            float z  = tanhf_(acc[5][mf][r] + bj[5]);
            float dec = softplusf_(acc[6][mf][r] + bj[6]);
            size_t idx = (size_t)row * H_SZ + j;
            float c1 = cx1[idx], c2 = cx2[idx];
            float cy1 = f1 * c1 + i1 * z;
            float cy2 = f2 * c2 + i2 * z;
            float ct  = cy2 + (cy1 - cy2) * __expf(-dec * dtv);
            float ht  = o * tanhf_(ct);
            out[idx]          = cy1;
            out[BH + idx]     = cy2;
            out[2 * BH + idx] = ht;
        }
    }
}

extern "C" void kernel_launch(void* const* d_in, const int* in_sizes, int n_in,
                              void* d_out, int out_size, void* d_ws, size_t ws_size,
                              hipStream_t stream) {
    const float* hx  = (const float*)d_in[0];
    const float* cx1 = (const float*)d_in[1];
    const float* cx2 = (const float*)d_in[2];
    const float* dt  = (const float*)d_in[4];
    const float* W   = (const float*)d_in[5];
    const float* b   = (const float*)d_in[6];
    float* out = (float*)d_out;

    if (ws_size >= WS_NEEDED) {
        char* bimg = (char*)d_ws;
        char* aimg = (char*)d_ws + AB_OFF;
        conv_b<<<dim3(NNB * NKT), dim3(448), 0, stream>>>(W, bimg);
        conv_a<<<dim3(NBX * 64), dim3(1024), 0, stream>>>(hx, aimg);
        lstm_gemm<<<dim3(NBX * NNB), dim3(512), 0, stream>>>(
            bimg, aimg, cx1, cx2, dt, b, out);
    } else {
        lstm_f32<<<dim3(NBX * NNB / 2), dim3(NTH), 0, stream>>>(
            hx, cx1, cx2, dt, W, b, out);
    }
}

// Round 15
// 532.791 us; speedup vs baseline: 1.1308x; 1.0598x over previous
//
#include <hip/hip_runtime.h>
#include <hip/hip_bf16.h>
#include <stdint.h>

// LSTMCell fused: g = hx @ W + b (M=8192,K=2048,N=7*2048) + gate math.
// R15 = R10 (best measured: 534.8 us total, 498 us main). Mw=64 (8 waves,
// 2/SIMD), in-order-lgkm-correct register pipeline: per step, 11 asm
// ds_read_b128 issued front (A t.1-3, B t+1 x7, A t+1.0), then 4 MFMA
// clusters gated by COUNTED lgkmcnt(11/10/9/8). B/A0 parity double-buffered.
// glds depth-3, vmcnt(4). Structural plateau: LDS-read service (~1056 cyc)
// + MFMA (~1086 cyc) per K-32 run serial on this CU across 9 schedule
// variants (+-3%); see R4-R14 post-mortems.

#define B_SZ 8192
#define D_SZ 2048
#define H_SZ 2048
#define NG   7
#define NW   (NG * H_SZ)          // 14336
#define BM   256
#define BN   32
#define BK   32
#define NKST (D_SZ / BK)          // 64
#define NBX  (B_SZ / BM)          // 32
#define NBY  (H_SZ / BN)          // 64

// bf16 tile images in ws:
//  W' : [by(64)][ks(64)] -> 224 rows x 32 k bf16 = 14336 B (XOR-swizzled)
//  hx': [bx(32)][ks(64)] -> 256 rows x 32 k bf16 = 16384 B (XOR-swizzled)
// Within a tile: row-major, 64 B/row, 16B chunk pc stores logical k-octet
// koct = pc ^ ((r>>1)&3).
#define WB_BYTES   ((size_t)NBY * NKST * 14336)   // 58,720,256
#define HXB_OFF    WB_BYTES
#define HXB_BYTES  ((size_t)NBX * NKST * 16384)   // 33,554,432
#define WS_NEEDED  (WB_BYTES + HXB_BYTES)         // 92,274,688

typedef __attribute__((ext_vector_type(8))) short bf16x8;
typedef __attribute__((ext_vector_type(4))) float f32x4;

__device__ __forceinline__ uint32_t cvtpk(float lo, float hi) {
    uint32_t r;
    asm("v_cvt_pk_bf16_f32 %0, %1, %2" : "=v"(r) : "v"(lo), "v"(hi));
    return r;
}
__device__ __forceinline__ void glds16(const void* g, void* l) {
    __builtin_amdgcn_global_load_lds(
        (const __attribute__((address_space(1))) uint32_t*)g,
        (__attribute__((address_space(3))) uint32_t*)l, 16, 0, 0);
}
__device__ __forceinline__ float sigmoidf_(float x) {
    return 1.0f / (1.0f + __expf(-x));
}
__device__ __forceinline__ float tanhf_(float x) {
    float ax = fabsf(x);
    float e = __expf(2.0f * ax);
    float t = 1.0f - 2.0f / (e + 1.0f);
    return copysignf(t, x);
}
__device__ __forceinline__ float softplusf_(float x) {
    return (x > 30.0f) ? x : __logf(1.0f + __expf(x));
}

// ---------------- convert W -> W' (bf16, transposed, swizzled) -------------
__global__ __launch_bounds__(896) void conv_w(const float* __restrict__ W,
                                              char* __restrict__ wb)
{
    const int by = blockIdx.x >> 6;
    const int ks = blockIdx.x & 63;
    const int u  = threadIdx.x;          // 0..895 = 224 rows x 4 chunks
    const int r  = u >> 2;               // row: g*32+n
    const int pc = u & 3;
    const int koct = pc ^ ((r >> 1) & 3);
    const int g  = r >> 5;
    const int n  = r & 31;
    const int col = g * H_SZ + by * BN + n;
    const float* src = W + (size_t)(ks * BK + koct * 8) * NW + col;
    float w0 = src[0];
    float w1 = src[(size_t)NW];
    float w2 = src[(size_t)2 * NW];
    float w3 = src[(size_t)3 * NW];
    float w4 = src[(size_t)4 * NW];
    float w5 = src[(size_t)5 * NW];
    float w6 = src[(size_t)6 * NW];
    float w7 = src[(size_t)7 * NW];
    uint4 o;
    o.x = cvtpk(w0, w1); o.y = cvtpk(w2, w3);
    o.z = cvtpk(w4, w5); o.w = cvtpk(w6, w7);
    *(uint4*)(wb + (size_t)blockIdx.x * 14336 + u * 16) = o;
}

// ---------------- convert hx -> hx' (bf16, swizzled) -----------------------
__global__ __launch_bounds__(1024) void conv_hx(const float* __restrict__ hx,
                                                char* __restrict__ hxb)
{
    const int bx = blockIdx.x >> 6;
    const int ks = blockIdx.x & 63;
    const int u  = threadIdx.x;          // 0..1023 = 256 rows x 4 chunks
    const int r  = u >> 2;
    const int pc = u & 3;
    const int koct = pc ^ ((r >> 1) & 3);
    const float* src = hx + (size_t)(bx * BM + r) * D_SZ + ks * BK + koct * 8;
    f32x4 a = *(const f32x4*)(src);
    f32x4 b = *(const f32x4*)(src + 4);
    uint4 o;
    o.x = cvtpk(a[0], a[1]); o.y = cvtpk(a[2], a[3]);
    o.z = cvtpk(b[0], b[1]); o.w = cvtpk(b[2], b[3]);
    *(uint4*)(hxb + (size_t)blockIdx.x * 16384 + u * 16) = o;
}

// ---------------- main bf16 kernel -----------------------------------------
#define NTH3 512
#define BUFB 30720                     // 16384 (A) + 14336 (B)

#define SB0 __builtin_amdgcn_sched_barrier(0)

__global__ __launch_bounds__(NTH3, 2) void lstm_bf16(
    const char* __restrict__ wb, const char* __restrict__ hxb,
    const float* __restrict__ cx1, const float* __restrict__ cx2,
    const float* __restrict__ dt, const float* __restrict__ bias,
    float* __restrict__ out)
{
    __shared__ char smem[4 * BUFB];   // 122880 B

    const int tid  = threadIdx.x;
    const int lane = tid & 63;
    const int wid  = tid >> 6;           // 0..7
    const int wm   = wid >> 1;           // 0..3  (64 rows each)
    const int wn   = wid & 1;            // 0..1  (16 cols/gate each)
    const int l15  = lane & 15;
    const int lg   = lane >> 4;

    // block order: XCD chunk, then by-pairs
    const int b0  = blockIdx.x;
    const int swz = (b0 & 7) * 256 + (b0 >> 3);
    const int by2 = swz >> 6;
    const int rem = swz & 63;
    const int bx  = rem >> 1;
    const int by  = by2 * 2 + (rem & 1);
    const int gm0 = bx * BM;
    const int n0  = by * BN;

    // fragment LDS byte addresses, XOR chunk = lg ^ ((l15>>1)&3)
    const int xch = (lg ^ ((l15 >> 1) & 3)) * 8;
    const uint32_t aAb = (uint32_t)(uintptr_t)smem + 2u * ((wm * 64 + l15) * 32 + xch);
    const uint32_t aBb = (uint32_t)(uintptr_t)smem + 16384u + 2u * ((wn * 16 + l15) * 32 + xch);
    const uint32_t aA0 = aAb,            aA1 = aAb + BUFB;
    const uint32_t aA2 = aAb + 2 * BUFB, aA3 = aAb + 3 * BUFB;
    const uint32_t aB0 = aBb,            aB1 = aBb + BUFB;
    const uint32_t aB2 = aBb + 2 * BUFB, aB3 = aBb + 3 * BUFB;

    // staging (4 glds/wave/stage, uniform vmcnt)
    const int lane16 = lane << 4;
    const char* hxp0 = hxb + (((size_t)(bx * NKST)) << 14) + (wid << 11) + lane16;
    const char* wbp0 = wb + (size_t)(by * NKST) * 14336 + wid * 1792 + lane16;
    char* dA0 = smem + (wid << 11);            char* dB0 = smem + 16384 + wid * 1792;
    char* dA1 = dA0 + BUFB;                    char* dB1 = dB0 + BUFB;
    char* dA2 = dA0 + 2 * BUFB;                char* dB2 = dB0 + 2 * BUFB;
    char* dA3 = dA0 + 3 * BUFB;                char* dB3 = dB0 + 3 * BUFB;

    f32x4 acc[NG][4];
    #pragma unroll
    for (int g = 0; g < NG; ++g)
        #pragma unroll
        for (int mf = 0; mf < 4; ++mf)
            acc[g][mf] = (f32x4){0.f, 0.f, 0.f, 0.f};

    // fragment registers: B and A0 parity double-buffered; A1-3 single
    bf16x8 fBE[NG], fBO[NG];
    bf16x8 fA0E, fA0O, fA1, fA2, fA3;

    #define ISSUE_A123(AAc) do {                                                   \
        asm volatile("ds_read_b128 %0, %1 offset:1024" : "=&v"(fA1) : "v"(AAc));   \
        asm volatile("ds_read_b128 %0, %1 offset:2048" : "=&v"(fA2) : "v"(AAc));   \
        asm volatile("ds_read_b128 %0, %1 offset:3072" : "=&v"(fA3) : "v"(AAc));   \
    } while (0)

    #define ISSUE_NEXT(ABn, AAn, FBN, FA0N) do {                                   \
        asm volatile("ds_read_b128 %0, %1"               : "=&v"(FBN[0]) : "v"(ABn)); \
        asm volatile("ds_read_b128 %0, %1 offset:2048"   : "=&v"(FBN[1]) : "v"(ABn)); \
        asm volatile("ds_read_b128 %0, %1 offset:4096"   : "=&v"(FBN[2]) : "v"(ABn)); \
        asm volatile("ds_read_b128 %0, %1 offset:6144"   : "=&v"(FBN[3]) : "v"(ABn)); \
        asm volatile("ds_read_b128 %0, %1 offset:8192"   : "=&v"(FBN[4]) : "v"(ABn)); \
        asm volatile("ds_read_b128 %0, %1 offset:10240"  : "=&v"(FBN[5]) : "v"(ABn)); \
        asm volatile("ds_read_b128 %0, %1 offset:12288"  : "=&v"(FBN[6]) : "v"(ABn)); \
        asm volatile("ds_read_b128 %0, %1"               : "=&v"(FA0N)   : "v"(AAn)); \
    } while (0)

    #define CLUSTER(FA, FBC, MF, LGN) do {                                         \
        asm volatile("s_waitcnt lgkmcnt(" #LGN ")" ::: "memory");                  \
        SB0;                                                                       \
        __builtin_amdgcn_s_setprio(1);                                             \
        _Pragma("unroll")                                                          \
        for (int g_ = 0; g_ < NG; ++g_)                                            \
            acc[g_][MF] = __builtin_amdgcn_mfma_f32_16x16x32_bf16(                 \
                FA, FBC[g_], acc[g_][MF], 0, 0, 0);                                \
        __builtin_amdgcn_s_setprio(0);                                             \
        SB0;                                                                       \
    } while (0)

    #define STAGE(SC) do {                                                         \
        glds16(hxp, dA##SC); glds16(hxp + 1024, dA##SC + 1024);                    \
        glds16(wbp, dB##SC);                                                       \
        if (lane < 48) glds16(wbp + 1024, dB##SC + 1024);                          \
        hxp += 16384; wbp += 14336;                                                \
    } while (0)

    #define STAGE_K(SC, K) do {                                                    \
        glds16(hxp0 + (K) * 16384, dA##SC);                                        \
        glds16(hxp0 + (K) * 16384 + 1024, dA##SC + 1024);                          \
        glds16(wbp0 + (K) * 14336, dB##SC);                                        \
        if (lane < 48) glds16(wbp0 + (K) * 14336 + 1024, dB##SC + 1024);           \
    } while (0)

    // Steady step t (c = t&3, cn = (t+1)&3, parity P):
    //  entry lgkm outstanding: {B(t)x7, A(t,0)} = 8; glds: {t+1:4, t+2:4}.
    //  vmcnt(4)+barrier publishes tile t+1; issue A(t,1-3) [c], B(t+1)+A0 [cn];
    //  stage(t+3) -> buf[(t+3)&3]; clusters gated lgkm 11/10/9/8.
    #define STEP_S(AAc, ABn, AAn, FBC, FBN, FA0C, FA0N, SC, VMN)  do {             \
        asm volatile("s_waitcnt vmcnt(" #VMN ")" ::: "memory");                    \
        __builtin_amdgcn_s_barrier();                                              \
        SB0;                                                                       \
        ISSUE_A123(AAc);                                                           \
        ISSUE_NEXT(ABn, AAn, FBN, FA0N);                                           \
        SB0;                                                                       \
        STAGE(SC);                                                                 \
        SB0;                                                                       \
        CLUSTER(FA0C, FBC, 0, 11);                                                 \
        CLUSTER(fA1,  FBC, 1, 10);                                                 \
        CLUSTER(fA2,  FBC, 2, 9);                                                  \
        CLUSTER(fA3,  FBC, 3, 8);                                                  \
    } while (0)

    #define STEP_N(AAc, ABn, AAn, FBC, FBN, FA0C, FA0N, VMN)  do {                 \
        asm volatile("s_waitcnt vmcnt(" #VMN ")" ::: "memory");                    \
        __builtin_amdgcn_s_barrier();                                              \
        SB0;                                                                       \
        ISSUE_A123(AAc);                                                           \
        ISSUE_NEXT(ABn, AAn, FBN, FA0N);                                           \
        SB0;                                                                       \
        CLUSTER(FA0C, FBC, 0, 11);                                                 \
        CLUSTER(fA1,  FBC, 1, 10);                                                 \
        CLUSTER(fA2,  FBC, 2, 9);                                                  \
        CLUSTER(fA3,  FBC, 3, 8);                                                  \
    } while (0)

    // prologue: stage tiles 0..2; publish tile 0; issue B(0)+A(0,0) -> E set
    STAGE_K(0, 0);
    STAGE_K(1, 1);
    STAGE_K(2, 2);
    const char* hxp = hxp0 + 3 * 16384;
    const char* wbp = wbp0 + 3 * 14336;
    asm volatile("s_waitcnt vmcnt(8)" ::: "memory");
    __builtin_amdgcn_s_barrier();
    SB0;
    ISSUE_NEXT(aB0, aA0, fBE, fA0E);
    SB0;

    // steady: t = 0..59 (15 x 4)
    #pragma unroll 1
    for (int it = 0; it < 15; ++it) {
        STEP_S(aA0, aB1, aA1, fBE, fBO, fA0E, fA0O, 3, 4);   // t%4==0 (E)
        STEP_S(aA1, aB2, aA2, fBO, fBE, fA0O, fA0E, 0, 4);   // t%4==1 (O)
        STEP_S(aA2, aB3, aA3, fBE, fBO, fA0E, fA0O, 1, 4);   // t%4==2 (E)
        STEP_S(aA3, aB0, aA0, fBO, fBE, fA0O, fA0E, 2, 4);   // t%4==3 (O)
    }
    // t=60 (E): stages tile 63 -> buf3
    STEP_S(aA0, aB1, aA1, fBE, fBO, fA0E, fA0O, 3, 4);
    // t=61 (O): no stage; vmcnt(4) publishes tile 62
    STEP_N(aA1, aB2, aA2, fBO, fBE, fA0O, fA0E, 4);
    // t=62 (E): vmcnt(0) publishes tile 63
    STEP_N(aA2, aB3, aA3, fBE, fBO, fA0E, fA0O, 0);
    // t=63 (O): final — only A123; counted drains 3/2/1/0
    ISSUE_A123(aA3);
    SB0;
    CLUSTER(fA0O, fBO, 0, 3);
    CLUSTER(fA1,  fBO, 1, 2);
    CLUSTER(fA2,  fBO, 2, 1);
    CLUSTER(fA3,  fBO, 3, 0);

    // epilogue
    const size_t BH = (size_t)B_SZ * H_SZ;
    const int j = n0 + wn * 16 + l15;
    float bj[NG];
    #pragma unroll
    for (int g = 0; g < NG; ++g) bj[g] = bias[g * H_SZ + j];

    #pragma unroll
    for (int mf = 0; mf < 4; ++mf) {
        #pragma unroll
        for (int r = 0; r < 4; ++r) {
            int row = gm0 + wm * 64 + mf * 16 + lg * 4 + r;
            float dtv = dt[row];
            float i1 = sigmoidf_(acc[0][mf][r] + bj[0]);
            float i2 = sigmoidf_(acc[1][mf][r] + bj[1]);
            float f1 = sigmoidf_(acc[2][mf][r] + bj[2]);
            float f2 = sigmoidf_(acc[3][mf][r] + bj[3]);
            float o  = sigmoidf_(acc[4][mf][r] + bj[4]);
            float z  = tanhf_(acc[5][mf][r] + bj[5]);
            float dec = softplusf_(acc[6][mf][r] + bj[6]);
            size_t idx = (size_t)row * H_SZ + j;
            float c1 = cx1[idx], c2 = cx2[idx];
            float cy1 = f1 * c1 + i1 * z;
            float cy2 = f2 * c2 + i2 * z;
            float ct  = cy2 + (cy1 - cy2) * __expf(-dec * dtv);
            float ht  = o * tanhf_(ct);
            out[idx]          = cy1;
            out[BH + idx]     = cy2;
            out[2 * BH + idx] = ht;
        }
    }
}

// ---------------- f32 fallback (R2, passed) --------------------------------
#define NTH  512
#define LDP  40
__global__ __launch_bounds__(NTH, 2) void lstm_f32(
    const float* __restrict__ hx, const float* __restrict__ cx1,
    const float* __restrict__ cx2, const float* __restrict__ dt,
    const float* __restrict__ W, const float* __restrict__ bias,
    float* __restrict__ out)
{
    __shared__ ushort sA[BM * LDP];
    __shared__ ushort sB[NG * BN * LDP];

    const int tid = threadIdx.x;
    const int nwg = gridDim.x;
    const int cpx = nwg >> 3;
    const int b0  = blockIdx.x;
    const int swz = (b0 & 7) * cpx + (b0 >> 3);
    const int bx  = swz & 31;
    const int by  = swz >> 5;
    const int gm0 = bx * BM;
    const int n0  = by * BN;

    const int lane = tid & 63;
    const int wid  = tid >> 6;
    const int wm   = wid >> 1;
    const int wn   = wid & 1;
    const int l15  = lane & 15;
    const int lg   = lane >> 4;

    const int ar0 = tid >> 2,          aq0 = tid & 3;
    const int ar1 = (tid + 512) >> 2,  aq1 = tid & 3;
    const bool hasB = (tid < 448);
    const int bg  = tid >> 6;
    const int bkq = (tid >> 3) & 7;
    const int bnq = tid & 7;

    f32x4 pa[4];
    f32x4 pb[4];

    auto issue_loads = [&](int K0) {
        {
            const float* p = hx + (size_t)(gm0 + ar0) * D_SZ + K0 + aq0 * 8;
            pa[0] = *(const f32x4*)(p);
            pa[1] = *(const f32x4*)(p + 4);
        }
        {
            const float* p = hx + (size_t)(gm0 + ar1) * D_SZ + K0 + aq1 * 8;
            pa[2] = *(const f32x4*)(p);
            pa[3] = *(const f32x4*)(p + 4);
        }
        if (hasB) {
            const float* p = W + (size_t)(K0 + bkq * 4) * NW + bg * H_SZ + n0 + bnq * 4;
            pb[0] = *(const f32x4*)(p);
            pb[1] = *(const f32x4*)(p + NW);
            pb[2] = *(const f32x4*)(p + 2 * NW);
            pb[3] = *(const f32x4*)(p + 3 * NW);
        }
    };

    auto store_lds = [&]() {
        {
            uint4 u;
            u.x = cvtpk(pa[0][0], pa[0][1]); u.y = cvtpk(pa[0][2], pa[0][3]);
            u.z = cvtpk(pa[1][0], pa[1][1]); u.w = cvtpk(pa[1][2], pa[1][3]);
            *(uint4*)(&sA[ar0 * LDP + aq0 * 8]) = u;
        }
        {
            uint4 u;
            u.x = cvtpk(pa[2][0], pa[2][1]); u.y = cvtpk(pa[2][2], pa[2][3]);
            u.z = cvtpk(pa[3][0], pa[3][1]); u.w = cvtpk(pa[3][2], pa[3][3]);
            *(uint4*)(&sA[ar1 * LDP + aq1 * 8]) = u;
        }
        if (hasB) {
            #pragma unroll
            for (int jj = 0; jj < 4; ++jj) {
                uint2 v;
                v.x = cvtpk(pb[0][jj], pb[1][jj]);
                v.y = cvtpk(pb[2][jj], pb[3][jj]);
                *(uint2*)(&sB[(bg * BN + bnq * 4 + jj) * LDP + bkq * 4]) = v;
            }
        }
    };

    f32x4 acc[NG][4];
    #pragma unroll
    for (int g = 0; g < NG; ++g)
        #pragma unroll
        for (int mf = 0; mf < 4; ++mf)
            acc[g][mf] = (f32x4){0.f, 0.f, 0.f, 0.f};

    int aoff[4];
    #pragma unroll
    for (int mf = 0; mf < 4; ++mf)
        aoff[mf] = (wm * 64 + mf * 16 + l15) * LDP + lg * 8;
    int boff[NG];
    #pragma unroll
    for (int g = 0; g < NG; ++g)
        boff[g] = (g * BN + wn * 16 + l15) * LDP + lg * 8;

    issue_loads(0);
    for (int kk = 0; kk < NKST; ++kk) {
        store_lds();
        __syncthreads();
        if (kk + 1 < NKST) issue_loads((kk + 1) * BK);

        bf16x8 af[4];
        #pragma unroll
        for (int mf = 0; mf < 4; ++mf)
            af[mf] = *(const bf16x8*)(&sA[aoff[mf]]);
        #pragma unroll
        for (int g = 0; g < NG; ++g) {
            bf16x8 bfr = *(const bf16x8*)(&sB[boff[g]]);
            #pragma unroll
            for (int mf = 0; mf < 4; ++mf)
                acc[g][mf] = __builtin_amdgcn_mfma_f32_16x16x32_bf16(
                    af[mf], bfr, acc[g][mf], 0, 0, 0);
        }
        __syncthreads();
    }

    const size_t BH = (size_t)B_SZ * H_SZ;
    const int j = n0 + wn * 16 + l15;
    float bj[NG];
    #pragma unroll
    for (int g = 0; g < NG; ++g) bj[g] = bias[g * H_SZ + j];

    #pragma unroll
    for (int mf = 0; mf < 4; ++mf) {
        #pragma unroll
        for (int r = 0; r < 4; ++r) {
            int row = gm0 + wm * 64 + mf * 16 + lg * 4 + r;
            float dtv = dt[row];
            float i1 = sigmoidf_(acc[0][mf][r] + bj[0]);
            float i2 = sigmoidf_(acc[1][mf][r] + bj[1]);
            float f1 = sigmoidf_(acc[2][mf][r] + bj[2]);
            float f2 = sigmoidf_(acc[3][mf][r] + bj[3]);
            float o  = sigmoidf_(acc[4][mf][r] + bj[4]);
            float z  = tanhf_(acc[5][mf][r] + bj[5]);
            float dec = softplusf_(acc[6][mf][r] + bj[6]);
            size_t idx = (size_t)row * H_SZ + j;
            float c1 = cx1[idx], c2 = cx2[idx];
            float cy1 = f1 * c1 + i1 * z;
            float cy2 = f2 * c2 + i2 * z;
            float ct  = cy2 + (cy1 - cy2) * __expf(-dec * dtv);
            float ht  = o * tanhf_(ct);
            out[idx]          = cy1;
            out[BH + idx]     = cy2;
            out[2 * BH + idx] = ht;
        }
    }
}

extern "C" void kernel_launch(void* const* d_in, const int* in_sizes, int n_in,
                              void* d_out, int out_size, void* d_ws, size_t ws_size,
                              hipStream_t stream) {
    const float* hx  = (const float*)d_in[0];
    const float* cx1 = (const float*)d_in[1];
    const float* cx2 = (const float*)d_in[2];
    const float* dt  = (const float*)d_in[4];
    const float* W   = (const float*)d_in[5];
    const float* b   = (const float*)d_in[6];
    float* out = (float*)d_out;

    if (ws_size >= WS_NEEDED) {
        char* wb  = (char*)d_ws;
        char* hxb = (char*)d_ws + HXB_OFF;
        conv_w<<<dim3(NBY * NKST), dim3(896), 0, stream>>>(W, wb);
        conv_hx<<<dim3(NBX * NKST), dim3(1024), 0, stream>>>(hx, hxb);
        lstm_bf16<<<dim3(NBX * NBY), dim3(NTH3), 0, stream>>>(
            wb, hxb, cx1, cx2, dt, b, out);
    } else {
        lstm_f32<<<dim3(NBX * NBY), dim3(NTH), 0, stream>>>(
            hx, cx1, cx2, dt, W, b, out);
    }
}